// Round 1
// baseline (722.827 us; speedup 1.0000x reference)
//
#include <hip/hip_runtime.h>
#include <math.h>

#define NLEVELS 16
#define TSIZE   (1u << 19)
#define HMASK   (TSIZE - 1u)
#define PRIME_Y 2654435761u
#define PRIME_Z 805459861u

// Level scales are computed on the HOST with double pow() so they bit-match
// CPython's GROWTH**l (l=15 lands ~1e-10 from 4095.0 — cannot be recomputed
// via repeated multiplication safely). Passed by value as kernel args.
struct Scales { float s[NLEVELS]; };

__device__ __forceinline__ unsigned umin_(unsigned a, unsigned b) { return a < b ? a : b; }

__global__ __launch_bounds__(256) void hashgrid_mlp_kernel(
    const float* __restrict__ gpos,    // [N,3]
    const float* __restrict__ gtable,  // [16, 2^19, 2]
    const float* __restrict__ gw1,     // [32,64]
    const float* __restrict__ gw2,     // [64,3]
    float* __restrict__ gout,          // [N,3]
    int npts, Scales sc)
{
    // Stage MLP weights in LDS. w1 transposed to [64][32] so the per-j dot
    // product reads 32 contiguous floats (vectorizes to ds_read_b128,
    // uniform-address broadcast -> no bank conflicts).
    __shared__ float w1t[64 * 32];
    __shared__ float w2s[64 * 3];
    const int tid = threadIdx.x;
    for (int e = tid; e < 32 * 64; e += 256) {
        int i = e >> 6, j = e & 63;       // gw1 is [i=32][j=64] row-major
        w1t[j * 32 + i] = gw1[e];
    }
    if (tid < 192) w2s[tid] = gw2[tid];
    __syncthreads();

    const int p = blockIdx.x * 256 + tid;
    if (p >= npts) return;

    const float px = gpos[3 * p + 0];
    const float py = gpos[3 * p + 1];
    const float pz = gpos[3 * p + 2];
    // contract_to_unisphere (bounded): [-1,1] -> [0,1]
    const float x = (px + 1.f) * 0.5f;
    const float y = (py + 1.f) * 0.5f;
    const float z = (pz + 1.f) * 0.5f;

    float enc[32];
    // dense levels 0..4: res = ceil(16*g^l - 1) + 1, res^3 <= 2^19
    static const unsigned kRes[5] = {16u, 25u, 34u, 49u, 71u};

#pragma unroll
    for (int l = 0; l < NLEVELS; ++l) {
        const float s = sc.s[l];
        const float fx = x * s + 0.5f;
        const float fy = y * s + 0.5f;
        const float fz = z * s + 0.5f;
        const float bx = floorf(fx), by = floorf(fy), bz = floorf(fz);
        const float tx = fx - bx, ty = fy - by, tz = fz - bz;
        const unsigned x0 = (unsigned)bx, y0 = (unsigned)by, z0 = (unsigned)bz;
        const float wx[2] = {1.f - tx, tx};
        const float wy[2] = {1.f - ty, ty};
        const float wz[2] = {1.f - tz, tz};
        const float2* tl = (const float2*)gtable + (size_t)l * TSIZE;
        float e0 = 0.f, e1 = 0.f;
        if (l < 5) {
            const unsigned R = kRes[l];
            const unsigned cx[2] = {umin_(x0, R - 1), umin_(x0 + 1u, R - 1)};
            const unsigned cy[2] = {umin_(y0, R - 1), umin_(y0 + 1u, R - 1)};
            const unsigned cz[2] = {umin_(z0, R - 1), umin_(z0 + 1u, R - 1)};
#pragma unroll
            for (int dz = 0; dz < 2; ++dz)
#pragma unroll
                for (int dy = 0; dy < 2; ++dy)
#pragma unroll
                    for (int dx = 0; dx < 2; ++dx) {
                        const unsigned idx = cx[dx] + cy[dy] * R + cz[dz] * R * R;
                        const float2 f = tl[idx];
                        const float w = wx[dx] * wy[dy] * wz[dz];
                        e0 += w * f.x;
                        e1 += w * f.y;
                    }
        } else {
            const unsigned hx[2] = {x0, x0 + 1u};
            const unsigned hy[2] = {y0 * PRIME_Y, y0 * PRIME_Y + PRIME_Y};
            const unsigned hz[2] = {z0 * PRIME_Z, z0 * PRIME_Z + PRIME_Z};
#pragma unroll
            for (int dz = 0; dz < 2; ++dz)
#pragma unroll
                for (int dy = 0; dy < 2; ++dy)
#pragma unroll
                    for (int dx = 0; dx < 2; ++dx) {
                        const unsigned idx = (hx[dx] ^ hy[dy] ^ hz[dz]) & HMASK;
                        const float2 f = tl[idx];
                        const float w = wx[dx] * wy[dy] * wz[dz];
                        e0 += w * f.x;
                        e1 += w * f.y;
                    }
        }
        enc[2 * l + 0] = e0;
        enc[2 * l + 1] = e1;
    }

    // MLP: h = relu(enc @ w1); feat = h @ w2; out = sigmoid(feat)
    float o0 = 0.f, o1 = 0.f, o2 = 0.f;
    for (int j = 0; j < 64; ++j) {
        const float* wr = &w1t[j * 32];
        float acc = 0.f;
#pragma unroll
        for (int i = 0; i < 32; ++i) acc += enc[i] * wr[i];
        acc = fmaxf(acc, 0.f);
        o0 += acc * w2s[3 * j + 0];
        o1 += acc * w2s[3 * j + 1];
        o2 += acc * w2s[3 * j + 2];
    }
    gout[3 * p + 0] = 1.f / (1.f + __expf(-o0));
    gout[3 * p + 1] = 1.f / (1.f + __expf(-o1));
    gout[3 * p + 2] = 1.f / (1.f + __expf(-o2));
}

extern "C" void kernel_launch(void* const* d_in, const int* in_sizes, int n_in,
                              void* d_out, int out_size, void* d_ws, size_t ws_size,
                              hipStream_t stream)
{
    const float* gpos   = (const float*)d_in[0];
    const float* gtable = (const float*)d_in[1];
    const float* gw1    = (const float*)d_in[2];
    const float* gw2    = (const float*)d_in[3];
    float* gout = (float*)d_out;
    const int npts = in_sizes[0] / 3;

    Scales sc;
    for (int l = 0; l < NLEVELS; ++l)
        sc.s[l] = (float)(16.0 * pow(1.447269237440378, (double)l) - 1.0);

    const int blocks = (npts + 255) / 256;
    hipLaunchKernelGGL(hashgrid_mlp_kernel, dim3(blocks), dim3(256), 0, stream,
                       gpos, gtable, gw1, gw2, gout, npts, sc);
}